// Round 4
// baseline (236.024 us; speedup 1.0000x reference)
//
#include <hip/hip_runtime.h>
#include <hip/hip_bf16.h>
#include <stdint.h>

#define NB 8
#define NP 12000
#define NM 32
#define NF 9
#define NC 64
#define NX 144
#define NCELL (144*144)          // 20736 = 64*324

#define PPW 8                    // pillars per wave
#define FEAT_WAVES ((NB*NP)/PPW) // 12000 (1500/batch -> no batch straddle)
#define FEAT_BLOCKS (FEAT_WAVES/4)
#define TILES_PER_B (NCELL/64)   // 324

typedef __attribute__((ext_vector_type(8)))  short bfrag8;
typedef __attribute__((ext_vector_type(16))) float accf16;
typedef float f32x4u __attribute__((ext_vector_type(4), aligned(4)));

// ws layout:
//   [0,2048)        btab: 2 c-tiles x 64 lanes x 8 bf16 (B-frag, BN-folded)
//   [2048,2304)     shift[c]
//   [4096,667648)   winner[b][cell] (8*20736 ints)
//   [667648,+42.47M) feat_cell[(b*NCELL+cell)*64 + c]  (winner cells only)
#define WS_BTAB  0
#define WS_SHIFT 2048
#define WS_WIN   4096
#define WS_CELL  667648
#define WS_NEED  (WS_CELL + (size_t)NB*NCELL*NC*4)

// Pass 1: last-write-wins winner (largest p wins) + BN-folded weight prep.
__global__ void winner_prep_kernel(const int* __restrict__ idx, int* __restrict__ winner,
                                   const float* __restrict__ conv_w,
                                   const float* __restrict__ gamma,
                                   const float* __restrict__ beta,
                                   const float* __restrict__ mean,
                                   const float* __restrict__ var,
                                   unsigned short* __restrict__ btab,
                                   float* __restrict__ shift)
{
    int t = blockIdx.x * blockDim.x + threadIdx.x;
    if (t < NB * NP) {
        int b = t / NP;
        int p = t - b * NP;
        int y = idx[t * 3 + 1];
        int x = idx[t * 3 + 2];
        x = x < 0 ? 0 : (x > 143 ? 143 : x);
        y = y < 0 ? 0 : (y > 143 ? 143 : y);
        atomicMax(&winner[b * NCELL + y * NX + x], p);   // init = -1
    }
    if (blockIdx.x == 0) {
        int tt = threadIdx.x;
        if (tt < 128) {
            int ct = tt >> 6, L = tt & 63;
            int c  = ct * 32 + (L & 31);
            int kq = L >> 5;
            float sc = gamma[c] * rsqrtf(var[c] + 1e-5f);
            unsigned short* dst = btab + (ct * 64 + L) * 8;
            #pragma unroll
            for (int j = 0; j < 8; ++j) {
                int k = kq * 8 + j;
                float w = (k < NF) ? conv_w[c * NF + k] * sc : 0.f;
                __hip_bfloat16 h = __float2bfloat16(w);
                dst[j] = *(unsigned short*)&h;
            }
        }
        if (tt < NC) {
            float sc = gamma[tt] * rsqrtf(var[tt] + 1e-5f);
            shift[tt] = beta[tt] - mean[tt] * sc;
        }
    }
}

__device__ __forceinline__ float max16(const accf16& a) {
    float t0 = fmaxf(fmaxf(a[0], a[1]),  fmaxf(a[2], a[3]));
    float t1 = fmaxf(fmaxf(a[4], a[5]),  fmaxf(a[6], a[7]));
    float t2 = fmaxf(fmaxf(a[8], a[9]),  fmaxf(a[10], a[11]));
    float t3 = fmaxf(fmaxf(a[12], a[13]), fmaxf(a[14], a[15]));
    return fmaxf(fmaxf(t0, t1), fmaxf(t2, t3));
}

// Pass 2: dense streaming conv+max (round-0 proven form). Winner/cell
// metadata for all 8 pillars hoisted to the top (wave-uniform, independent
// chains). Winner pillars write their 64 channels as one 256B aligned row.
// NOTE: this round the kernel is launched TWICE (idempotent) as an ablation
// probe — dur_us delta vs the single-launch baseline measures T_feat.
template <bool COMPACT>
__global__ void __launch_bounds__(256) feat_dense_kernel(
    const float* __restrict__ pillars,
    const unsigned short* __restrict__ btab,
    const float* __restrict__ shift,
    const int*   __restrict__ idx,
    const int*   __restrict__ winner,
    float* __restrict__ feat_cell,
    float* __restrict__ out)
{
    int tid  = threadIdx.x;
    int lane = tid & 63;
    int wave = blockIdx.x * 4 + (tid >> 6);
    int row  = lane & 31;
    int kq   = lane >> 5;
    int b    = wave / (NP / PPW);            // 1500 waves per batch, no straddle

    bfrag8 b0 = *(const bfrag8*)(btab + lane * 8);
    bfrag8 b1 = *(const bfrag8*)(btab + (64 + lane) * 8);
    float  sh = shift[lane];
    accf16 z  = {};

    // hoisted per-pillar metadata (wave-uniform)
    int cellv[PPW];
    bool winv[PPW];
    #pragma unroll
    for (int i = 0; i < PPW; ++i) {
        int pil = wave * PPW + i;
        int y = idx[pil * 3 + 1];
        int x = idx[pil * 3 + 2];
        x = x < 0 ? 0 : (x > 143 ? 143 : x);
        y = y < 0 ? 0 : (y > 143 ? 143 : y);
        int cell = y * NX + x;
        cellv[i] = cell;
        winv[i]  = (winner[b * NCELL + cell] == pil - b * NP);
    }

    const float* wbase = pillars + (size_t)wave * (PPW * NM * NF) + row * NF;

    #pragma unroll
    for (int g = 0; g < PPW / 4; ++g) {
        f32x4u lo[4], hi[4];
        float  e8[4];
        #pragma unroll
        for (int i = 0; i < 4; ++i) {
            const float* base = wbase + (size_t)(g * 4 + i) * (NM * NF);
            lo[i] = *(const f32x4u*)(base);
            hi[i] = *(const f32x4u*)(base + 4);
            e8[i] = base[8];
        }
        #pragma unroll
        for (int i = 0; i < 4; ++i) {
            int pi = g * 4 + i;
            float s[8];
            s[0] = kq ? e8[i] : lo[i][0];
            s[1] = kq ? 0.f   : lo[i][1];
            s[2] = kq ? 0.f   : lo[i][2];
            s[3] = kq ? 0.f   : lo[i][3];
            s[4] = kq ? 0.f   : hi[i][0];
            s[5] = kq ? 0.f   : hi[i][1];
            s[6] = kq ? 0.f   : hi[i][2];
            s[7] = kq ? 0.f   : hi[i][3];
            bfrag8 a;
            #pragma unroll
            for (int j = 0; j < 8; ++j) {
                __hip_bfloat16 h = __float2bfloat16(s[j]);
                a[j] = *(short*)&h;
            }
            accf16 acc0 = __builtin_amdgcn_mfma_f32_32x32x16_bf16(a, b0, z, 0, 0, 0);
            accf16 acc1 = __builtin_amdgcn_mfma_f32_32x32x16_bf16(a, b1, z, 0, 0, 0);

            float v0 = max16(acc0);
            float v1 = max16(acc1);
            v0 = fmaxf(v0, __shfl_xor(v0, 32));
            v1 = fmaxf(v1, __shfl_xor(v1, 32));
            float r = (lane < 32) ? v0 : v1;   // channel = lane
            r += sh;
            r = r > 0.f ? r : 0.f;

            if (winv[pi]) {                    // wave-uniform branch
                if (COMPACT) {
                    feat_cell[((size_t)(b * NCELL + cellv[pi])) * NC + lane] = r;
                } else {
                    out[((size_t)(b * NC + lane)) * NCELL + cellv[pi]] = r;
                }
            }
        }
    }
}

// Pass 3: dense LDS transpose (round-0 proven form).
__global__ void __launch_bounds__(256) scatter_t_kernel(
    const int* __restrict__ winner,
    const float* __restrict__ feat_cell,
    float* __restrict__ out)
{
    __shared__ float ld[NC * 68];            // stride 68 floats, 17.4 KB
    int tile = blockIdx.x;                   // [0, NB*324)
    int b    = tile / TILES_PER_B;
    int cb   = (tile - b * TILES_PER_B) * 64;
    int t    = threadIdx.x;

    // load phase: thread t -> cell = t>>2, quarter q = t&3 (16 ch as 4 float4)
    {
        int cell = t >> 2, q = t & 3;
        int w = winner[b * NCELL + cb + cell];
        const f32x4u* src = (const f32x4u*)(feat_cell +
                             ((size_t)(b * NCELL + cb + cell)) * NC);
        #pragma unroll
        for (int k = 0; k < 4; ++k) {
            f32x4u v = {0.f, 0.f, 0.f, 0.f};
            if (w >= 0) v = src[q * 4 + k];  // masked load: losers skip fetch
            int c = q * 16 + k * 4;
            ld[(c + 0) * 68 + cell] = v[0];  // transpose on LDS write
            ld[(c + 1) * 68 + cell] = v[1];
            ld[(c + 2) * 68 + cell] = v[2];
            ld[(c + 3) * 68 + cell] = v[3];
        }
    }
    __syncthreads();
    // write phase: thread t -> c = t>>2, quarter qq = t&3 (16 cells as 4 float4)
    {
        int c = t >> 2, qq = t & 3;
        float* o = out + ((size_t)(b * NC + c)) * NCELL + cb + qq * 16;
        const float* lrow = ld + c * 68 + qq * 16;
        #pragma unroll
        for (int k = 0; k < 4; ++k) {
            *(f32x4u*)(o + k * 4) = *(const f32x4u*)(lrow + k * 4);
        }
    }
}

extern "C" void kernel_launch(void* const* d_in, const int* in_sizes, int n_in,
                              void* d_out, int out_size, void* d_ws, size_t ws_size,
                              hipStream_t stream) {
    const float* pillars = (const float*)d_in[0];
    const int*   idx     = (const int*)d_in[1];
    const float* conv_w  = (const float*)d_in[2];
    const float* gamma   = (const float*)d_in[3];
    const float* beta    = (const float*)d_in[4];
    const float* mean    = (const float*)d_in[5];
    const float* var     = (const float*)d_in[6];
    float* out = (float*)d_out;

    char* ws = (char*)d_ws;
    unsigned short* btab      = (unsigned short*)(ws + WS_BTAB);
    float*          shift     = (float*)(ws + WS_SHIFT);
    int*            winner    = (int*)(ws + WS_WIN);
    float*          feat_cell = (float*)(ws + WS_CELL);

    const bool compact = ws_size >= WS_NEED;   // constant per session

    hipMemsetAsync(winner, 0xFF, (size_t)NB * NCELL * sizeof(int), stream);
    winner_prep_kernel<<<(NB * NP + 255) / 256, 256, 0, stream>>>(
        idx, winner, conv_w, gamma, beta, mean, var, btab, shift);

    if (compact) {
        // ABLATION PROBE: feat launched twice (idempotent). dur_us delta vs
        // single-launch baseline (~210 us on this container class) = T_feat.
        feat_dense_kernel<true><<<FEAT_BLOCKS, 256, 0, stream>>>(
            pillars, btab, shift, idx, winner, feat_cell, out);
        feat_dense_kernel<true><<<FEAT_BLOCKS, 256, 0, stream>>>(
            pillars, btab, shift, idx, winner, feat_cell, out);
        scatter_t_kernel<<<NB * TILES_PER_B, 256, 0, stream>>>(
            winner, feat_cell, out);
    } else {
        hipMemsetAsync(out, 0, (size_t)out_size * sizeof(float), stream);
        feat_dense_kernel<false><<<FEAT_BLOCKS, 256, 0, stream>>>(
            pillars, btab, shift, idx, winner, feat_cell, out);
    }
}

// Round 5
// 206.968 us; speedup vs baseline: 1.1404x; 1.1404x over previous
//
#include <hip/hip_runtime.h>
#include <hip/hip_bf16.h>
#include <stdint.h>

#define NB 8
#define NP 12000
#define NM 32
#define NF 9
#define NC 64
#define NX 144
#define NCELL (144*144)          // 20736 = 64*324

#define PPW 8                    // pillars per wave
#define FEAT_WAVES ((NB*NP)/PPW) // 12000 (1500/batch -> no batch straddle)
#define FEAT_BLOCKS (FEAT_WAVES/4)
#define TILES_PER_B (NCELL/64)   // 324

typedef __attribute__((ext_vector_type(8)))  short bfrag8;
typedef __attribute__((ext_vector_type(16))) float accf16;
typedef float f32x4u __attribute__((ext_vector_type(4), aligned(4)));

// ws layout:
//   [0,2048)        btab: 2 c-tiles x 64 lanes x 8 bf16 (B-frag, BN-folded)
//   [2048,2304)     shift[c]
//   [4096,667648)   winner[b][cell] (8*20736 ints)
//   [667648,+42.47M) feat_cell[(b*NCELL+cell)*64 + c]  (winner cells only)
#define WS_BTAB  0
#define WS_SHIFT 2048
#define WS_WIN   4096
#define WS_CELL  667648
#define WS_NEED  (WS_CELL + (size_t)NB*NCELL*NC*4)

// Session accounting (rounds 0-4 ablations):
//   T_feat ~= 25.5 us (double-launch probe, round 4), ~82% of BW floor.
//   T_scatter ~= 15 us (96 MB moved, near floor). T_prep ~= 3 us.
//   Our GPU work ~= 50 us of the ~210 us timed window; the rest is
//   harness-fixed (432 MB poison fills @ ~64 us each in-window).
//   Round 2 proved: list-gather (locality loss) costs +23 us; round 3
//   proved: metadata-chain removal is fully TLP-hidden (0 us). This
//   structure is the measured optimum.

// Pass 1: last-write-wins winner (largest p wins) + BN-folded weight prep.
__global__ void winner_prep_kernel(const int* __restrict__ idx, int* __restrict__ winner,
                                   const float* __restrict__ conv_w,
                                   const float* __restrict__ gamma,
                                   const float* __restrict__ beta,
                                   const float* __restrict__ mean,
                                   const float* __restrict__ var,
                                   unsigned short* __restrict__ btab,
                                   float* __restrict__ shift)
{
    int t = blockIdx.x * blockDim.x + threadIdx.x;
    if (t < NB * NP) {
        int b = t / NP;
        int p = t - b * NP;
        int y = idx[t * 3 + 1];
        int x = idx[t * 3 + 2];
        x = x < 0 ? 0 : (x > 143 ? 143 : x);
        y = y < 0 ? 0 : (y > 143 ? 143 : y);
        atomicMax(&winner[b * NCELL + y * NX + x], p);   // init = -1
    }
    if (blockIdx.x == 0) {
        int tt = threadIdx.x;
        if (tt < 128) {
            int ct = tt >> 6, L = tt & 63;
            int c  = ct * 32 + (L & 31);
            int kq = L >> 5;
            float sc = gamma[c] * rsqrtf(var[c] + 1e-5f);
            unsigned short* dst = btab + (ct * 64 + L) * 8;
            #pragma unroll
            for (int j = 0; j < 8; ++j) {
                int k = kq * 8 + j;
                float w = (k < NF) ? conv_w[c * NF + k] * sc : 0.f;
                __hip_bfloat16 h = __float2bfloat16(w);
                dst[j] = *(unsigned short*)&h;
            }
        }
        if (tt < NC) {
            float sc = gamma[tt] * rsqrtf(var[tt] + 1e-5f);
            shift[tt] = beta[tt] - mean[tt] * sc;
        }
    }
}

__device__ __forceinline__ float max16(const accf16& a) {
    float t0 = fmaxf(fmaxf(a[0], a[1]),  fmaxf(a[2], a[3]));
    float t1 = fmaxf(fmaxf(a[4], a[5]),  fmaxf(a[6], a[7]));
    float t2 = fmaxf(fmaxf(a[8], a[9]),  fmaxf(a[10], a[11]));
    float t3 = fmaxf(fmaxf(a[12], a[13]), fmaxf(a[14], a[15]));
    return fmaxf(fmaxf(t0, t1), fmaxf(t2, t3));
}

// Pass 2: dense streaming conv+max. Winner/cell metadata for all 8 pillars
// hoisted to the top (wave-uniform, independent chains). Winner pillars write
// their 64 channels as one 256B aligned row to feat_cell[b][cell][*].
template <bool COMPACT>
__global__ void __launch_bounds__(256) feat_dense_kernel(
    const float* __restrict__ pillars,
    const unsigned short* __restrict__ btab,
    const float* __restrict__ shift,
    const int*   __restrict__ idx,
    const int*   __restrict__ winner,
    float* __restrict__ feat_cell,
    float* __restrict__ out)
{
    int tid  = threadIdx.x;
    int lane = tid & 63;
    int wave = blockIdx.x * 4 + (tid >> 6);
    int row  = lane & 31;
    int kq   = lane >> 5;
    int b    = wave / (NP / PPW);            // 1500 waves per batch, no straddle

    bfrag8 b0 = *(const bfrag8*)(btab + lane * 8);
    bfrag8 b1 = *(const bfrag8*)(btab + (64 + lane) * 8);
    float  sh = shift[lane];
    accf16 z  = {};

    // hoisted per-pillar metadata (wave-uniform)
    int cellv[PPW];
    bool winv[PPW];
    #pragma unroll
    for (int i = 0; i < PPW; ++i) {
        int pil = wave * PPW + i;
        int y = idx[pil * 3 + 1];
        int x = idx[pil * 3 + 2];
        x = x < 0 ? 0 : (x > 143 ? 143 : x);
        y = y < 0 ? 0 : (y > 143 ? 143 : y);
        int cell = y * NX + x;
        cellv[i] = cell;
        winv[i]  = (winner[b * NCELL + cell] == pil - b * NP);
    }

    const float* wbase = pillars + (size_t)wave * (PPW * NM * NF) + row * NF;

    #pragma unroll
    for (int g = 0; g < PPW / 4; ++g) {
        f32x4u lo[4], hi[4];
        float  e8[4];
        #pragma unroll
        for (int i = 0; i < 4; ++i) {
            const float* base = wbase + (size_t)(g * 4 + i) * (NM * NF);
            lo[i] = *(const f32x4u*)(base);
            hi[i] = *(const f32x4u*)(base + 4);
            e8[i] = base[8];
        }
        #pragma unroll
        for (int i = 0; i < 4; ++i) {
            int pi = g * 4 + i;
            float s[8];
            s[0] = kq ? e8[i] : lo[i][0];
            s[1] = kq ? 0.f   : lo[i][1];
            s[2] = kq ? 0.f   : lo[i][2];
            s[3] = kq ? 0.f   : lo[i][3];
            s[4] = kq ? 0.f   : hi[i][0];
            s[5] = kq ? 0.f   : hi[i][1];
            s[6] = kq ? 0.f   : hi[i][2];
            s[7] = kq ? 0.f   : hi[i][3];
            bfrag8 a;
            #pragma unroll
            for (int j = 0; j < 8; ++j) {
                __hip_bfloat16 h = __float2bfloat16(s[j]);
                a[j] = *(short*)&h;
            }
            accf16 acc0 = __builtin_amdgcn_mfma_f32_32x32x16_bf16(a, b0, z, 0, 0, 0);
            accf16 acc1 = __builtin_amdgcn_mfma_f32_32x32x16_bf16(a, b1, z, 0, 0, 0);

            float v0 = max16(acc0);
            float v1 = max16(acc1);
            v0 = fmaxf(v0, __shfl_xor(v0, 32));
            v1 = fmaxf(v1, __shfl_xor(v1, 32));
            float r = (lane < 32) ? v0 : v1;   // channel = lane
            r += sh;
            r = r > 0.f ? r : 0.f;

            if (winv[pi]) {                    // wave-uniform branch
                if (COMPACT) {
                    feat_cell[((size_t)(b * NCELL + cellv[pi])) * NC + lane] = r;
                } else {
                    out[((size_t)(b * NC + lane)) * NCELL + cellv[pi]] = r;
                }
            }
        }
    }
}

// Pass 3: dense LDS transpose. Block = (b, 64-cell tile). Read feat_cell
// coalesced (loser lanes exec-masked -> load skipped), zero-fill losers,
// transpose via LDS, write out coalesced float4. Covers every out element.
__global__ void __launch_bounds__(256) scatter_t_kernel(
    const int* __restrict__ winner,
    const float* __restrict__ feat_cell,
    float* __restrict__ out)
{
    __shared__ float ld[NC * 68];            // stride 68 floats, 17.4 KB
    int tile = blockIdx.x;                   // [0, NB*324)
    int b    = tile / TILES_PER_B;
    int cb   = (tile - b * TILES_PER_B) * 64;
    int t    = threadIdx.x;

    // load phase: thread t -> cell = t>>2, quarter q = t&3 (16 ch as 4 float4)
    {
        int cell = t >> 2, q = t & 3;
        int w = winner[b * NCELL + cb + cell];
        const f32x4u* src = (const f32x4u*)(feat_cell +
                             ((size_t)(b * NCELL + cb + cell)) * NC);
        #pragma unroll
        for (int k = 0; k < 4; ++k) {
            f32x4u v = {0.f, 0.f, 0.f, 0.f};
            if (w >= 0) v = src[q * 4 + k];  // masked load: losers skip fetch
            int c = q * 16 + k * 4;
            ld[(c + 0) * 68 + cell] = v[0];  // transpose on LDS write
            ld[(c + 1) * 68 + cell] = v[1];
            ld[(c + 2) * 68 + cell] = v[2];
            ld[(c + 3) * 68 + cell] = v[3];
        }
    }
    __syncthreads();
    // write phase: thread t -> c = t>>2, quarter qq = t&3 (16 cells as 4 float4)
    {
        int c = t >> 2, qq = t & 3;
        float* o = out + ((size_t)(b * NC + c)) * NCELL + cb + qq * 16;
        const float* lrow = ld + c * 68 + qq * 16;
        #pragma unroll
        for (int k = 0; k < 4; ++k) {
            *(f32x4u*)(o + k * 4) = *(const f32x4u*)(lrow + k * 4);
        }
    }
}

extern "C" void kernel_launch(void* const* d_in, const int* in_sizes, int n_in,
                              void* d_out, int out_size, void* d_ws, size_t ws_size,
                              hipStream_t stream) {
    const float* pillars = (const float*)d_in[0];
    const int*   idx     = (const int*)d_in[1];
    const float* conv_w  = (const float*)d_in[2];
    const float* gamma   = (const float*)d_in[3];
    const float* beta    = (const float*)d_in[4];
    const float* mean    = (const float*)d_in[5];
    const float* var     = (const float*)d_in[6];
    float* out = (float*)d_out;

    char* ws = (char*)d_ws;
    unsigned short* btab      = (unsigned short*)(ws + WS_BTAB);
    float*          shift     = (float*)(ws + WS_SHIFT);
    int*            winner    = (int*)(ws + WS_WIN);
    float*          feat_cell = (float*)(ws + WS_CELL);

    const bool compact = ws_size >= WS_NEED;   // constant per session

    hipMemsetAsync(winner, 0xFF, (size_t)NB * NCELL * sizeof(int), stream);
    winner_prep_kernel<<<(NB * NP + 255) / 256, 256, 0, stream>>>(
        idx, winner, conv_w, gamma, beta, mean, var, btab, shift);

    if (compact) {
        feat_dense_kernel<true><<<FEAT_BLOCKS, 256, 0, stream>>>(
            pillars, btab, shift, idx, winner, feat_cell, out);
        scatter_t_kernel<<<NB * TILES_PER_B, 256, 0, stream>>>(
            winner, feat_cell, out);
    } else {
        hipMemsetAsync(out, 0, (size_t)out_size * sizeof(float), stream);
        feat_dense_kernel<false><<<FEAT_BLOCKS, 256, 0, stream>>>(
            pillars, btab, shift, idx, winner, feat_cell, out);
    }
}